// Round 9
// baseline (244.715 us; speedup 1.0000x reference)
//
#include <hip/hip_runtime.h>
#include <stdint.h>

typedef __attribute__((ext_vector_type(8))) __bf16 bf16x8;
typedef __attribute__((ext_vector_type(16))) float f32x16;

__device__ __forceinline__ unsigned short f2bf(float f) {
  union { float f; unsigned int u; } v;
  v.f = f;
  unsigned int u = v.u;
  return (unsigned short)((u + 0x7FFFu + ((u >> 16) & 1u)) >> 16);
}

union BFrag { unsigned short u[8]; unsigned int w[4]; bf16x8 v; };

__device__ __forceinline__ f32x16 mfma32(bf16x8 a, bf16x8 b, f32x16 c) {
  return __builtin_amdgcn_mfma_f32_32x32x16_bf16(a, b, c, 0, 0, 0);
}

#define GLOAD_LDS16(gptr, lptr)                                                \
  __builtin_amdgcn_global_load_lds(                                           \
      (const __attribute__((address_space(1))) void*)(gptr),                  \
      (__attribute__((address_space(3))) void*)(lptr), 16, 0, 0)

// ---------------- x gather + fp32->bf16 (region-token order) ----------------
__global__ __launch_bounds__(256) void k_xgather(const float* __restrict__ x,
                                                 unsigned short* __restrict__ xb) {
  int idx = blockIdx.x * 256 + threadIdx.x;
  int m = idx >> 6;
  int seg = (idx & 63) << 3;
  int r = m >> 8, n = m & 255;
  int a = r / 12, b = r - a * 12;
  int ii = n >> 4, jj = n & 15;
  long g = (long)((a * 16 + ii) * 192 + b * 16 + jj);
  const float4* p = (const float4*)(x + g * 512 + seg);
  float4 v0 = p[0], v1 = p[1];
  union { unsigned short u[8]; int4 v; } o;
  o.u[0] = f2bf(v0.x); o.u[1] = f2bf(v0.y); o.u[2] = f2bf(v0.z); o.u[3] = f2bf(v0.w);
  o.u[4] = f2bf(v1.x); o.u[5] = f2bf(v1.y); o.u[6] = f2bf(v1.z); o.u[7] = f2bf(v1.w);
  *(int4*)(xb + (size_t)m * 512 + seg) = o.v;
}

// ---------------- plain fp32->bf16 ----------------
__global__ __launch_bounds__(256) void k_cvt(const float* __restrict__ s,
                                             unsigned short* __restrict__ d, int n8) {
  int i = blockIdx.x * 256 + threadIdx.x;
  if (i >= n8) return;
  const float4* p = (const float4*)(s + (size_t)i * 8);
  float4 a = p[0], b = p[1];
  union { unsigned short u[8]; int4 v; } o;
  o.u[0] = f2bf(a.x); o.u[1] = f2bf(a.y); o.u[2] = f2bf(a.z); o.u[3] = f2bf(a.w);
  o.u[4] = f2bf(b.x); o.u[5] = f2bf(b.y); o.u[6] = f2bf(b.z); o.u[7] = f2bf(b.w);
  *(int4*)(d + (size_t)i * 8) = o.v;
}

// ---------------- GEMM (m97-style; q scaled by 1/8 for natural-domain softmax) ----
template<int MODE, int NBN>
__global__ __launch_bounds__(256, 2) void k_gemm(
    const unsigned short* __restrict__ A, const unsigned short* __restrict__ B,
    const float* __restrict__ bias,
    unsigned short* __restrict__ qb, unsigned short* __restrict__ kb,
    unsigned short* __restrict__ vtb, float* __restrict__ out) {
  __shared__ unsigned short As[8192];
  __shared__ unsigned short Bs[8192];
  int t = threadIdx.x;
  constexpr int NWG = NBN * 288;
  int d0 = blockIdx.x;
  int tl = (d0 & 7) * (NWG >> 3) + (d0 >> 3);
  int bm = tl / NBN, bn = tl % NBN;

  int w = t >> 6, lane = t & 63;
  int l31 = lane & 31, lh = lane >> 5;
  int wr = w >> 1, wc = w & 1;

  int srow = t >> 3, cseg = t & 7;
  int csw = (cseg ^ (srow & 7)) << 3;
  int ldsWaveOff = (t >> 6) << 10;

  f32x16 acc[2][2];
  for (int i = 0; i < 2; ++i)
    for (int j = 0; j < 2; ++j)
      for (int e = 0; e < 16; ++e) acc[i][j][e] = 0.0f;

  const unsigned short* Ag = A + (size_t)(bm * 128 + srow) * 512 + csw;
  const unsigned short* Bg = B + (size_t)(bn * 128 + srow) * 512 + csw;

  for (int ks = 0; ks < 8; ++ks) {
#pragma unroll
    for (int rnd = 0; rnd < 4; ++rnd) {
      GLOAD_LDS16(Ag + (size_t)rnd * 32 * 512 + ks * 64,
                  (char*)As + ldsWaveOff + rnd * 4096);
      GLOAD_LDS16(Bg + (size_t)rnd * 32 * 512 + ks * 64,
                  (char*)Bs + ldsWaveOff + rnd * 4096);
    }
    __syncthreads();
#pragma unroll
    for (int kt = 0; kt < 4; ++kt) {
      bf16x8 af[2], bfr[2];
#pragma unroll
      for (int mt = 0; mt < 2; ++mt) {
        int r = wr * 64 + mt * 32 + l31;
        af[mt] = *(const bf16x8*)((const char*)As + r * 128 +
                                  ((kt * 32 + lh * 16) ^ ((r & 7) << 4)));
      }
#pragma unroll
      for (int nt = 0; nt < 2; ++nt) {
        int r = wc * 64 + nt * 32 + l31;
        bfr[nt] = *(const bf16x8*)((const char*)Bs + r * 128 +
                                   ((kt * 32 + lh * 16) ^ ((r & 7) << 4)));
      }
#pragma unroll
      for (int mt = 0; mt < 2; ++mt)
#pragma unroll
        for (int nt = 0; nt < 2; ++nt)
          acc[mt][nt] = mfma32(af[mt], bfr[nt], acc[mt][nt]);
    }
    __syncthreads();
  }

  int nBase = bn * 128 + wc * 64;
  int mBase = bm * 128 + wr * 64;
#pragma unroll
  for (int nt = 0; nt < 2; ++nt) {
    int nn = nBase + nt * 32 + l31;
    float bs = bias[nn];
    if (MODE == 0) {
      int tsel = nn >> 9, rem = nn & 511;
      int hh = rem >> 6, d = rem & 63;
#pragma unroll
      for (int mt = 0; mt < 2; ++mt) {
#pragma unroll
        for (int q = 0; q < 4; ++q) {
          int m0 = mBase + mt * 32 + q * 8 + lh * 4;
          int r = m0 >> 8, tok = m0 & 255;
          size_t base = (size_t)(r * 8 + hh) * 16384;
          if (tsel == 0) {
#pragma unroll
            for (int j = 0; j < 4; ++j)
              qb[base + (size_t)(tok + j) * 64 + d] = f2bf((acc[mt][nt][q * 4 + j] + bs) * 0.125f);
          } else if (tsel == 1) {
#pragma unroll
            for (int j = 0; j < 4; ++j)
              kb[base + (size_t)(tok + j) * 64 + d] = f2bf(acc[mt][nt][q * 4 + j] + bs);
          } else {
            unsigned long long pv = 0;
#pragma unroll
            for (int j = 0; j < 4; ++j)
              pv |= (unsigned long long)f2bf(acc[mt][nt][q * 4 + j] + bs) << (16 * j);
            *(unsigned long long*)(vtb + base + (size_t)d * 256 + tok) = pv;
          }
        }
      }
    } else {
#pragma unroll
      for (int mt = 0; mt < 2; ++mt) {
#pragma unroll
        for (int q = 0; q < 4; ++q) {
          int m0 = mBase + mt * 32 + q * 8 + lh * 4;
          int r = m0 >> 8;
          int a = r / 12, bcol = r - a * 12;
#pragma unroll
          for (int j = 0; j < 4; ++j) {
            int tok = (m0 & 255) + j;
            int ii = tok >> 4, jj = tok & 15;
            long gg = (long)((a * 16 + ii) * 192 + bcol * 16 + jj);
            out[gg * 512 + nn] = acc[mt][nt][q * 4 + j] + bs;
          }
        }
      }
    }
  }
}

// ---------------- fused region attention v6: KVBLK=32, fits 128 regs --------
// 8 waves x 32 i-rows; j in 8 sub-tiles of 32. Combined VGPR+AGPR ~115 -> fits
// the 128 cap of (512,4) without spill -> 2 blocks/CU (16 waves).
// LDS: K [0,32K) swz | S^T [32K,48K) [32j][256i]swz | V [48K,56K) [64d][64j]swz
//      (staged every 2nd iter) | band table [57344, 57728).
__global__ __launch_bounds__(512, 4) void k_attn6(
    const unsigned short* __restrict__ qb, const unsigned short* __restrict__ kb,
    const unsigned short* __restrict__ vtb, const float* __restrict__ pe_w,
    unsigned short* __restrict__ ctxb) {
  extern __shared__ char lds[];
  int rh = blockIdx.x;
  int h = rh & 7;
  int t = threadIdx.x, w = t >> 6, lane = t & 63;
  int l31 = lane & 31, lh = lane >> 5;
  int iw = w << 5;                     // wave's i base (32 rows)
  int myi = iw + l31;

  const unsigned short* Qg = qb + (size_t)rh * 16384;
  const unsigned short* Kg = kb + (size_t)rh * 16384;
  const unsigned short* Vg = vtb + (size_t)rh * 16384;
  const float* wh = pe_w + h * 15;

  // ---- stage K (4 rounds x 64 rows x 128B) ----
#pragma unroll
  for (int rr = 0; rr < 4; ++rr) {
    int row = rr * 64 + (t >> 3);
    GLOAD_LDS16(Kg + row * 64 + (((t & 7) ^ (row & 7)) << 3), lds + rr * 8192 + t * 16);
  }
  // ---- band weight table: entry[k] = (w[k-40], w[k-39]) bf16 pair ----
  if (t < 96) {
    int dlo = t - 40, dhi = t - 39;
    unsigned int lo = (dlo >= 0 && dlo < 15) ? f2bf(wh[dlo]) : 0;
    unsigned int hi = (dhi >= 0 && dhi < 15) ? f2bf(wh[dhi]) : 0;
    *(unsigned int*)(lds + 57344 + t * 4) = lo | (hi << 16);
  }
  // ---- Q fragments direct to regs (pre-scaled by 1/8 in gemm epilogue) ----
  bf16x8 qf[4];
#pragma unroll
  for (int kt = 0; kt < 4; ++kt)
    qf[kt] = *(const bf16x8*)(Qg + (size_t)myi * 64 + kt * 16 + lh * 8);
  __syncthreads();

  float m = -3.0e38f, l = 0.0f;
  f32x16 acco[2];
#pragma unroll
  for (int nt = 0; nt < 2; ++nt)
#pragma unroll
    for (int e = 0; e < 16; ++e) acco[nt][e] = 0.0f;

#pragma unroll
  for (int it = 0; it < 8; ++it) {
    // ---- QK^T sub-tile: 32 j rows; sacc rows j (reg), cols i (lane) ----
    f32x16 sacc;
#pragma unroll
    for (int e = 0; e < 16; ++e) sacc[e] = 0.0f;
    {
      int kr = it * 32 + l31;
#pragma unroll
      for (int kt = 0; kt < 4; ++kt) {
        bf16x8 kf = *(const bf16x8*)(lds + kr * 128 + (((kt * 2 + lh) ^ (kr & 7)) << 4));
        sacc = mfma32(kf, qf[kt], sacc);
      }
    }
    __syncthreads();   // (A) prev sub-tile's conv/PV LDS reads retired

    // ---- stage V-tile (64 j) every other iter; consumed after sync B ----
    if ((it & 1) == 0) {
      int row = t >> 3;
      GLOAD_LDS16(Vg + row * 256 + it * 32 + (((t & 7) ^ (row & 7)) << 3),
                  lds + 49152 + t * 16);
    }

    // ---- store S^T sub-tile [32j][256i] (bf16, XOR-swizzled) ----
    {
      int i2 = myi * 2;
#pragma unroll
      for (int rg = 0; rg < 16; ++rg) {
        int jl = (rg & 3) + 8 * (rg >> 2) + 4 * lh;   // local j 0..31
        *(unsigned short*)(lds + 32768 + jl * 512 + (i2 ^ ((jl & 7) << 4))) =
            f2bf(sacc[rg]);
      }
    }
    __syncthreads();   // (B) S^T visible; V-tile loaded (vmcnt drained)

    // ---- banded conv: sacc += S^T x Wband (4 ktg chunks per wave) ----
    {
      int jl = l31;
#pragma unroll
      for (int u = 0; u < 4; ++u) {
        int ktg = 2 * w + u - 1;
        if (ktg >= 0 && ktg < 16) {
          BFrag bb;
          int d0 = 16 * u + 8 * lh - l31 + 31;   // == ktg*16+lh*8-myi+47
#pragma unroll
          for (int e2 = 0; e2 < 4; ++e2)
            bb.w[e2] = *(const unsigned int*)(lds + 57344 + (d0 + 2 * e2) * 4);
          bf16x8 sfr = *(const bf16x8*)(lds + 32768 + jl * 512 +
                                        ((ktg * 32 + lh * 16) ^ ((jl & 7) << 4)));
          sacc = mfma32(sfr, bb.v, sacc);
        }
      }
    }

    // ---- exact online softmax; P packed to bf16 in the exp loop ----
    unsigned int pk[8];
    {
      float pm = -3.0e38f;
#pragma unroll
      for (int e = 0; e < 16; ++e) pm = fmaxf(pm, sacc[e]);
      pm = fmaxf(pm, __shfl_xor(pm, 32));
      float mn = fmaxf(m, pm);
      float f = __expf(m - mn);
      float ts = 0.0f;
#pragma unroll
      for (int u = 0; u < 8; ++u) {
        float p0 = __expf(sacc[2 * u] - mn);
        float p1 = __expf(sacc[2 * u + 1] - mn);
        ts += p0;
        ts += p1;
        pk[u] = (unsigned int)f2bf(p0) | ((unsigned int)f2bf(p1) << 16);
      }
      ts += __shfl_xor(ts, 32);
      l = (it == 0) ? ts : l * f + ts;
      m = mn;
      if (it != 0) {
#pragma unroll
        for (int rg = 0; rg < 16; ++rg) {
          float g = __shfl(f, (rg & 3) + 8 * (rg >> 2) + 4 * lh);
          acco[0][rg] *= g;
          acco[1][rg] *= g;
        }
      }
    }

    // ---- PV: assemble P frags (lh-swap) and MFMA with V half-tile ----
    {
      unsigned int sw[8];
#pragma unroll
      for (int u = 0; u < 8; ++u) sw[u] = (unsigned int)__shfl_xor((int)pk[u], 32);
      BFrag pf0, pf1;
      if (lh == 0) {
        pf0.w[0] = pk[0]; pf0.w[1] = pk[1]; pf0.w[2] = sw[0]; pf0.w[3] = sw[1];
        pf1.w[0] = pk[4]; pf1.w[1] = pk[5]; pf1.w[2] = sw[4]; pf1.w[3] = sw[5];
      } else {
        pf0.w[0] = sw[2]; pf0.w[1] = sw[3]; pf0.w[2] = pk[2]; pf0.w[3] = pk[3];
        pf1.w[0] = sw[6]; pf1.w[1] = sw[7]; pf1.w[2] = pk[6]; pf1.w[3] = pk[7];
      }
      int kj0 = (it & 1) * 2;        // which half of the 64-j V tile
#pragma unroll
      for (int nt = 0; nt < 2; ++nt) {
        int vr = nt * 32 + l31;
        bf16x8 vf0 = *(const bf16x8*)(lds + 49152 + vr * 128 +
                                      (((kj0 * 2 + lh) ^ (vr & 7)) << 4));
        bf16x8 vf1 = *(const bf16x8*)(lds + 49152 + vr * 128 +
                                      ((((kj0 + 1) * 2 + lh) ^ (vr & 7)) << 4));
        acco[nt] = mfma32(pf0.v, vf0, acco[nt]);
        acco[nt] = mfma32(pf1.v, vf1, acco[nt]);
      }
    }
  }

  // ---- epilogue: normalize by 1/l and store ----
  float inv = 1.0f / l;
  int r256 = (rh >> 3) * 256;
  int chbase = h * 64;
#pragma unroll
  for (int rg = 0; rg < 16; ++rg) {
    int cr = (rg & 3) + 8 * (rg >> 2) + 4 * lh;
    float g = __shfl(inv, cr);
    int i = iw + cr;
    size_t rowoff = (size_t)(r256 + i) * 512 + chbase;
    ctxb[rowoff + l31] = f2bf(acco[0][rg] * g);
    ctxb[rowoff + 32 + l31] = f2bf(acco[1][rg] * g);
  }
}

extern "C" void kernel_launch(void* const* d_in, const int* in_sizes, int n_in,
                              void* d_out, int out_size, void* d_ws, size_t ws_size,
                              hipStream_t stream) {
  const float* x = (const float*)d_in[0];
  const float* Wqkv = (const float*)d_in[1];
  const float* bqkv = (const float*)d_in[2];
  const float* Wproj = (const float*)d_in[3];
  const float* bproj = (const float*)d_in[4];
  const float* pew = (const float*)d_in[5];
  // d_in[6] = pe_b: constant per softmax row -> cancels exactly; skipped.

  char* ws = (char*)d_ws;
  unsigned short* xb = (unsigned short*)ws;                       // later reused as ctx
  unsigned short* wqkvb = (unsigned short*)(ws + 37748736);
  unsigned short* wprojb = (unsigned short*)(ws + 39321600);
  unsigned short* qb = (unsigned short*)(ws + 39845888);
  unsigned short* kb = (unsigned short*)(ws + 77594624);
  unsigned short* vtb = (unsigned short*)(ws + 115343360);

  (void)hipFuncSetAttribute((const void*)k_attn6,
                            hipFuncAttributeMaxDynamicSharedMemorySize, 163840);

  k_xgather<<<9216, 256, 0, stream>>>(x, xb);
  k_cvt<<<384, 256, 0, stream>>>(Wqkv, wqkvb, 98304);
  k_cvt<<<128, 256, 0, stream>>>(Wproj, wprojb, 32768);
  k_gemm<0, 12><<<3456, 256, 0, stream>>>(xb, wqkvb, bqkv, qb, kb, vtb, nullptr);
  k_attn6<<<1152, 512, 57728, stream>>>(qb, kb, vtb, pew, xb);
  k_gemm<1, 4><<<1152, 256, 0, stream>>>(xb, wprojb, bproj, nullptr, nullptr, nullptr,
                                         (float*)d_out);
}

// Round 10
// 227.331 us; speedup vs baseline: 1.0765x; 1.0765x over previous
//
#include <hip/hip_runtime.h>
#include <stdint.h>

typedef __attribute__((ext_vector_type(8))) __bf16 bf16x8;
typedef __attribute__((ext_vector_type(16))) float f32x16;

__device__ __forceinline__ unsigned short f2bf(float f) {
  union { float f; unsigned int u; } v;
  v.f = f;
  unsigned int u = v.u;
  return (unsigned short)((u + 0x7FFFu + ((u >> 16) & 1u)) >> 16);
}

union BFrag { unsigned short u[8]; unsigned int w[4]; bf16x8 v; };

__device__ __forceinline__ f32x16 mfma32(bf16x8 a, bf16x8 b, f32x16 c) {
  return __builtin_amdgcn_mfma_f32_32x32x16_bf16(a, b, c, 0, 0, 0);
}

#define GLOAD_LDS16(gptr, lptr)                                                \
  __builtin_amdgcn_global_load_lds(                                           \
      (const __attribute__((address_space(1))) void*)(gptr),                  \
      (__attribute__((address_space(3))) void*)(lptr), 16, 0, 0)

// ---------------- x gather + fp32->bf16 (region-token order) ----------------
__global__ __launch_bounds__(256) void k_xgather(const float* __restrict__ x,
                                                 unsigned short* __restrict__ xb) {
  int idx = blockIdx.x * 256 + threadIdx.x;
  int m = idx >> 6;
  int seg = (idx & 63) << 3;
  int r = m >> 8, n = m & 255;
  int a = r / 12, b = r - a * 12;
  int ii = n >> 4, jj = n & 15;
  long g = (long)((a * 16 + ii) * 192 + b * 16 + jj);
  const float4* p = (const float4*)(x + g * 512 + seg);
  float4 v0 = p[0], v1 = p[1];
  union { unsigned short u[8]; int4 v; } o;
  o.u[0] = f2bf(v0.x); o.u[1] = f2bf(v0.y); o.u[2] = f2bf(v0.z); o.u[3] = f2bf(v0.w);
  o.u[4] = f2bf(v1.x); o.u[5] = f2bf(v1.y); o.u[6] = f2bf(v1.z); o.u[7] = f2bf(v1.w);
  *(int4*)(xb + (size_t)m * 512 + seg) = o.v;
}

// ---------------- plain fp32->bf16 ----------------
__global__ __launch_bounds__(256) void k_cvt(const float* __restrict__ s,
                                             unsigned short* __restrict__ d, int n8) {
  int i = blockIdx.x * 256 + threadIdx.x;
  if (i >= n8) return;
  const float4* p = (const float4*)(s + (size_t)i * 8);
  float4 a = p[0], b = p[1];
  union { unsigned short u[8]; int4 v; } o;
  o.u[0] = f2bf(a.x); o.u[1] = f2bf(a.y); o.u[2] = f2bf(a.z); o.u[3] = f2bf(a.w);
  o.u[4] = f2bf(b.x); o.u[5] = f2bf(b.y); o.u[6] = f2bf(b.z); o.u[7] = f2bf(b.w);
  *(int4*)(d + (size_t)i * 8) = o.v;
}

// ---------------- GEMM (m97-style; q scaled by 1/8 for natural-domain softmax) ----
template<int MODE, int NBN>
__global__ __launch_bounds__(256, 2) void k_gemm(
    const unsigned short* __restrict__ A, const unsigned short* __restrict__ B,
    const float* __restrict__ bias,
    unsigned short* __restrict__ qb, unsigned short* __restrict__ kb,
    unsigned short* __restrict__ vtb, float* __restrict__ out) {
  __shared__ unsigned short As[8192];
  __shared__ unsigned short Bs[8192];
  int t = threadIdx.x;
  constexpr int NWG = NBN * 288;
  int d0 = blockIdx.x;
  int tl = (d0 & 7) * (NWG >> 3) + (d0 >> 3);
  int bm = tl / NBN, bn = tl % NBN;

  int w = t >> 6, lane = t & 63;
  int l31 = lane & 31, lh = lane >> 5;
  int wr = w >> 1, wc = w & 1;

  int srow = t >> 3, cseg = t & 7;
  int csw = (cseg ^ (srow & 7)) << 3;
  int ldsWaveOff = (t >> 6) << 10;

  f32x16 acc[2][2];
  for (int i = 0; i < 2; ++i)
    for (int j = 0; j < 2; ++j)
      for (int e = 0; e < 16; ++e) acc[i][j][e] = 0.0f;

  const unsigned short* Ag = A + (size_t)(bm * 128 + srow) * 512 + csw;
  const unsigned short* Bg = B + (size_t)(bn * 128 + srow) * 512 + csw;

  for (int ks = 0; ks < 8; ++ks) {
#pragma unroll
    for (int rnd = 0; rnd < 4; ++rnd) {
      GLOAD_LDS16(Ag + (size_t)rnd * 32 * 512 + ks * 64,
                  (char*)As + ldsWaveOff + rnd * 4096);
      GLOAD_LDS16(Bg + (size_t)rnd * 32 * 512 + ks * 64,
                  (char*)Bs + ldsWaveOff + rnd * 4096);
    }
    __syncthreads();
#pragma unroll
    for (int kt = 0; kt < 4; ++kt) {
      bf16x8 af[2], bfr[2];
#pragma unroll
      for (int mt = 0; mt < 2; ++mt) {
        int r = wr * 64 + mt * 32 + l31;
        af[mt] = *(const bf16x8*)((const char*)As + r * 128 +
                                  ((kt * 32 + lh * 16) ^ ((r & 7) << 4)));
      }
#pragma unroll
      for (int nt = 0; nt < 2; ++nt) {
        int r = wc * 64 + nt * 32 + l31;
        bfr[nt] = *(const bf16x8*)((const char*)Bs + r * 128 +
                                   ((kt * 32 + lh * 16) ^ ((r & 7) << 4)));
      }
#pragma unroll
      for (int mt = 0; mt < 2; ++mt)
#pragma unroll
        for (int nt = 0; nt < 2; ++nt)
          acc[mt][nt] = mfma32(af[mt], bfr[nt], acc[mt][nt]);
    }
    __syncthreads();
  }

  int nBase = bn * 128 + wc * 64;
  int mBase = bm * 128 + wr * 64;
#pragma unroll
  for (int nt = 0; nt < 2; ++nt) {
    int nn = nBase + nt * 32 + l31;
    float bs = bias[nn];
    if (MODE == 0) {
      int tsel = nn >> 9, rem = nn & 511;
      int hh = rem >> 6, d = rem & 63;
#pragma unroll
      for (int mt = 0; mt < 2; ++mt) {
#pragma unroll
        for (int q = 0; q < 4; ++q) {
          int m0 = mBase + mt * 32 + q * 8 + lh * 4;
          int r = m0 >> 8, tok = m0 & 255;
          size_t base = (size_t)(r * 8 + hh) * 16384;
          if (tsel == 0) {
#pragma unroll
            for (int j = 0; j < 4; ++j)
              qb[base + (size_t)(tok + j) * 64 + d] = f2bf((acc[mt][nt][q * 4 + j] + bs) * 0.125f);
          } else if (tsel == 1) {
#pragma unroll
            for (int j = 0; j < 4; ++j)
              kb[base + (size_t)(tok + j) * 64 + d] = f2bf(acc[mt][nt][q * 4 + j] + bs);
          } else {
            unsigned long long pv = 0;
#pragma unroll
            for (int j = 0; j < 4; ++j)
              pv |= (unsigned long long)f2bf(acc[mt][nt][q * 4 + j] + bs) << (16 * j);
            *(unsigned long long*)(vtb + base + (size_t)d * 256 + tok) = pv;
          }
        }
      }
    } else {
#pragma unroll
      for (int mt = 0; mt < 2; ++mt) {
#pragma unroll
        for (int q = 0; q < 4; ++q) {
          int m0 = mBase + mt * 32 + q * 8 + lh * 4;
          int r = m0 >> 8;
          int a = r / 12, bcol = r - a * 12;
#pragma unroll
          for (int j = 0; j < 4; ++j) {
            int tok = (m0 & 255) + j;
            int ii = tok >> 4, jj = tok & 15;
            long gg = (long)((a * 16 + ii) * 192 + bcol * 16 + jj);
            out[gg * 512 + nn] = acc[mt][nt][q * 4 + j] + bs;
          }
        }
      }
    }
  }
}

// ---------------- fused region attention v7: pipelined, 1 barrier/sub-tile --
// (512,2): no spill. KVBLK=32, 8 sub-tiles. Double-buffered S^T and V; each
// segment mixes conv-MFMA(t) + QK-MFMA(t+1) + softmax-VALU(t) + store(t+1) + PV(t).
// LDS: K [0,32K) | sbuf0 [32K,48K) sbuf1 [48K,64K) [32j][256i]swz |
//      vbuf0 [64K,72K) vbuf1 [72K,80K) [64d][64j]swz | band [81920,82304).
__global__ __launch_bounds__(512, 2) void k_attn7(
    const unsigned short* __restrict__ qb, const unsigned short* __restrict__ kb,
    const unsigned short* __restrict__ vtb, const float* __restrict__ pe_w,
    unsigned short* __restrict__ ctxb) {
  extern __shared__ char lds[];
  int rh = blockIdx.x;
  int h = rh & 7;
  int t = threadIdx.x, w = t >> 6, lane = t & 63;
  int l31 = lane & 31, lh = lane >> 5;
  int iw = w << 5;
  int myi = iw + l31;

  const unsigned short* Qg = qb + (size_t)rh * 16384;
  const unsigned short* Kg = kb + (size_t)rh * 16384;
  const unsigned short* Vg = vtb + (size_t)rh * 16384;
  const float* wh = pe_w + h * 15;

  // ---- stage K (4 rounds x 64 rows x 128B) + V tile0 + band table ----
#pragma unroll
  for (int rr = 0; rr < 4; ++rr) {
    int row = rr * 64 + (t >> 3);
    GLOAD_LDS16(Kg + row * 64 + (((t & 7) ^ (row & 7)) << 3), lds + rr * 8192 + t * 16);
  }
  {
    int row = t >> 3;
    GLOAD_LDS16(Vg + row * 256 + (((t & 7) ^ (row & 7)) << 3), lds + 65536 + t * 16);
  }
  if (t < 96) {
    int dlo = t - 40, dhi = t - 39;
    unsigned int lo = (dlo >= 0 && dlo < 15) ? f2bf(wh[dlo]) : 0;
    unsigned int hi = (dhi >= 0 && dhi < 15) ? f2bf(wh[dhi]) : 0;
    *(unsigned int*)(lds + 81920 + t * 4) = lo | (hi << 16);
  }
  bf16x8 qf[4];
#pragma unroll
  for (int kt = 0; kt < 4; ++kt)
    qf[kt] = *(const bf16x8*)(Qg + (size_t)myi * 64 + kt * 16 + lh * 8);
  __syncthreads();   // K, V0, band visible

  float m = -3.0e38f, l = 0.0f;
  f32x16 acco[2];
#pragma unroll
  for (int nt = 0; nt < 2; ++nt)
#pragma unroll
    for (int e = 0; e < 16; ++e) acco[nt][e] = 0.0f;

  f32x16 sc[2];   // sc[it&1]=current (QK+conv), sc[(it+1)&1]=next QK (static idx)

  // ---- prologue: QK(0) + store S^T(0) ----
#pragma unroll
  for (int e = 0; e < 16; ++e) sc[0][e] = 0.0f;
  {
    int kr = l31;
#pragma unroll
    for (int kt = 0; kt < 4; ++kt) {
      bf16x8 kf = *(const bf16x8*)(lds + kr * 128 + (((kt * 2 + lh) ^ (kr & 7)) << 4));
      sc[0] = mfma32(kf, qf[kt], sc[0]);
    }
  }
  {
    int i2 = myi * 2;
#pragma unroll
    for (int rg = 0; rg < 16; ++rg) {
      int jl = (rg & 3) + 8 * (rg >> 2) + 4 * lh;
      *(unsigned short*)(lds + 32768 + jl * 512 + (i2 ^ ((jl & 7) << 4))) =
          f2bf(sc[0][rg]);
    }
  }
  __syncthreads();   // S^T(0) visible

#pragma unroll
  for (int it = 0; it < 8; ++it) {
    const int cur = it & 1, nxt = cur ^ 1;
    char* sbuf = lds + 32768 + cur * 16384;
    char* sbufN = lds + 32768 + nxt * 16384;
    char* vbuf = lds + 65536 + ((it >> 1) & 1) * 8192;

    // ---- banded conv: sc[cur] += S^T(it) x Wband ----
    {
      int jl = l31;
#pragma unroll
      for (int u = 0; u < 4; ++u) {
        int ktg = 2 * w + u - 1;
        if (ktg >= 0 && ktg < 16) {
          BFrag bb;
          int d0 = 16 * u + 8 * lh - l31 + 31;
#pragma unroll
          for (int e2 = 0; e2 < 4; ++e2)
            bb.w[e2] = *(const unsigned int*)(lds + 81920 + (d0 + 2 * e2) * 4);
          bf16x8 sfr = *(const bf16x8*)(sbuf + jl * 512 +
                                        ((ktg * 32 + lh * 16) ^ ((jl & 7) << 4)));
          sc[cur] = mfma32(sfr, bb.v, sc[cur]);
        }
      }
    }

    // ---- QK(it+1) -> sc[nxt] (independent chain, interleaves with above) ----
    if (it < 7) {
#pragma unroll
      for (int e = 0; e < 16; ++e) sc[nxt][e] = 0.0f;
      int kr = (it + 1) * 32 + l31;
#pragma unroll
      for (int kt = 0; kt < 4; ++kt) {
        bf16x8 kf = *(const bf16x8*)(lds + kr * 128 + (((kt * 2 + lh) ^ (kr & 7)) << 4));
        sc[nxt] = mfma32(kf, qf[kt], sc[nxt]);
      }
    }

    // ---- online softmax on sc[cur]; P packed to bf16 ----
    unsigned int pk[8];
    {
      float pm = -3.0e38f;
#pragma unroll
      for (int e = 0; e < 16; ++e) pm = fmaxf(pm, sc[cur][e]);
      pm = fmaxf(pm, __shfl_xor(pm, 32));
      float mn = fmaxf(m, pm);
      float f = __expf(m - mn);
      float ts = 0.0f;
#pragma unroll
      for (int u = 0; u < 8; ++u) {
        float p0 = __expf(sc[cur][2 * u] - mn);
        float p1 = __expf(sc[cur][2 * u + 1] - mn);
        ts += p0;
        ts += p1;
        pk[u] = (unsigned int)f2bf(p0) | ((unsigned int)f2bf(p1) << 16);
      }
      ts += __shfl_xor(ts, 32);
      l = (it == 0) ? ts : l * f + ts;
      m = mn;
      if (it != 0) {
#pragma unroll
        for (int rg = 0; rg < 16; ++rg) {
          float g = __shfl(f, (rg & 3) + 8 * (rg >> 2) + 4 * lh);
          acco[0][rg] *= g;
          acco[1][rg] *= g;
        }
      }
    }

    // ---- store S^T(it+1) from sc[nxt] ----
    if (it < 7) {
      int i2 = myi * 2;
#pragma unroll
      for (int rg = 0; rg < 16; ++rg) {
        int jl = (rg & 3) + 8 * (rg >> 2) + 4 * lh;
        *(unsigned short*)(sbufN + jl * 512 + (i2 ^ ((jl & 7) << 4))) =
            f2bf(sc[nxt][rg]);
      }
    }

    // ---- stage V tile (it/2+1) on even it <= 4 ----
    if ((it & 1) == 0 && it <= 4) {
      int row = t >> 3;
      int jb64 = (it / 2 + 1) * 64;
      GLOAD_LDS16(Vg + row * 256 + jb64 + (((t & 7) ^ (row & 7)) << 3),
                  lds + 65536 + (((it / 2 + 1) & 1) * 8192) + t * 16);
    }

    // ---- PV(it): assemble P frags (lh-swap) and MFMA with V half-tile ----
    {
      unsigned int sw[8];
#pragma unroll
      for (int u = 0; u < 8; ++u) sw[u] = (unsigned int)__shfl_xor((int)pk[u], 32);
      BFrag pf0, pf1;
      if (lh == 0) {
        pf0.w[0] = pk[0]; pf0.w[1] = pk[1]; pf0.w[2] = sw[0]; pf0.w[3] = sw[1];
        pf1.w[0] = pk[4]; pf1.w[1] = pk[5]; pf1.w[2] = sw[4]; pf1.w[3] = sw[5];
      } else {
        pf0.w[0] = sw[2]; pf0.w[1] = sw[3]; pf0.w[2] = pk[2]; pf0.w[3] = pk[3];
        pf1.w[0] = sw[6]; pf1.w[1] = sw[7]; pf1.w[2] = pk[6]; pf1.w[3] = pk[7];
      }
      int kj0 = (it & 1) * 2;
#pragma unroll
      for (int nt = 0; nt < 2; ++nt) {
        int vr = nt * 32 + l31;
        bf16x8 vf0 = *(const bf16x8*)(vbuf + vr * 128 +
                                      (((kj0 * 2 + lh) ^ (vr & 7)) << 4));
        bf16x8 vf1 = *(const bf16x8*)(vbuf + vr * 128 +
                                      ((((kj0 + 1) * 2 + lh) ^ (vr & 7)) << 4));
        acco[nt] = mfma32(pf0.v, vf0, acco[nt]);
        acco[nt] = mfma32(pf1.v, vf1, acco[nt]);
      }
    }

    __syncthreads();
  }

  // ---- epilogue: normalize by 1/l and store ----
  float inv = 1.0f / l;
  int r256 = (rh >> 3) * 256;
  int chbase = h * 64;
#pragma unroll
  for (int rg = 0; rg < 16; ++rg) {
    int cr = (rg & 3) + 8 * (rg >> 2) + 4 * lh;
    float g = __shfl(inv, cr);
    int i = iw + cr;
    size_t rowoff = (size_t)(r256 + i) * 512 + chbase;
    ctxb[rowoff + l31] = f2bf(acco[0][rg] * g);
    ctxb[rowoff + 32 + l31] = f2bf(acco[1][rg] * g);
  }
}

extern "C" void kernel_launch(void* const* d_in, const int* in_sizes, int n_in,
                              void* d_out, int out_size, void* d_ws, size_t ws_size,
                              hipStream_t stream) {
  const float* x = (const float*)d_in[0];
  const float* Wqkv = (const float*)d_in[1];
  const float* bqkv = (const float*)d_in[2];
  const float* Wproj = (const float*)d_in[3];
  const float* bproj = (const float*)d_in[4];
  const float* pew = (const float*)d_in[5];
  // d_in[6] = pe_b: constant per softmax row -> cancels exactly; skipped.

  char* ws = (char*)d_ws;
  unsigned short* xb = (unsigned short*)ws;                       // later reused as ctx
  unsigned short* wqkvb = (unsigned short*)(ws + 37748736);
  unsigned short* wprojb = (unsigned short*)(ws + 39321600);
  unsigned short* qb = (unsigned short*)(ws + 39845888);
  unsigned short* kb = (unsigned short*)(ws + 77594624);
  unsigned short* vtb = (unsigned short*)(ws + 115343360);

  (void)hipFuncSetAttribute((const void*)k_attn7,
                            hipFuncAttributeMaxDynamicSharedMemorySize, 163840);

  k_xgather<<<9216, 256, 0, stream>>>(x, xb);
  k_cvt<<<384, 256, 0, stream>>>(Wqkv, wqkvb, 98304);
  k_cvt<<<128, 256, 0, stream>>>(Wproj, wprojb, 32768);
  k_gemm<0, 12><<<3456, 256, 0, stream>>>(xb, wqkvb, bqkv, qb, kb, vtb, nullptr);
  k_attn7<<<1152, 512, 82304, stream>>>(qb, kb, vtb, pew, xb);
  k_gemm<1, 4><<<1152, 256, 0, stream>>>(xb, wprojb, bproj, nullptr, nullptr, nullptr,
                                         (float*)d_out);
}